// Round 1
// baseline (1965.622 us; speedup 1.0000x reference)
//
#include <hip/hip_runtime.h>
#include <cstdint>
#include <cstddef>

// Problem constants (fixed instance per reference file)
#define N0C 1982464
#define N1C 123904
#define N2C 11264
#define N3C 1024
// D_IN=128, D_H=256, D_OUT=47

// ---------------------------------------------------------------------------
// CSR build: histogram -> exclusive scan -> scatter (src indices grouped by dst)
// ---------------------------------------------------------------------------
__global__ __launch_bounds__(256) void hist_k(const int* __restrict__ dst, int* __restrict__ cnt, int E) {
    int i = blockIdx.x * 256 + threadIdx.x;
    if (i < E) atomicAdd(&cnt[dst[i]], 1);
}

// per-block scan of 1024 elements (4/thread), writes exclusive scan + block sum
__global__ __launch_bounds__(256) void scan1_k(const int* __restrict__ in, int* __restrict__ out,
                                               int* __restrict__ bsum, int n) {
    __shared__ int sd[256];
    int t = threadIdx.x;
    int base = blockIdx.x * 1024 + t * 4;
    int v0 = (base + 0 < n) ? in[base + 0] : 0;
    int v1 = (base + 1 < n) ? in[base + 1] : 0;
    int v2 = (base + 2 < n) ? in[base + 2] : 0;
    int v3 = (base + 3 < n) ? in[base + 3] : 0;
    sd[t] = v0 + v1 + v2 + v3;
    __syncthreads();
    for (int off = 1; off < 256; off <<= 1) {
        int tmp = 0;
        if (t >= off) tmp = sd[t - off];
        __syncthreads();
        if (t >= off) sd[t] += tmp;
        __syncthreads();
    }
    int run = (t > 0) ? sd[t - 1] : 0;
    if (base + 0 < n) out[base + 0] = run; run += v0;
    if (base + 1 < n) out[base + 1] = run; run += v1;
    if (base + 2 < n) out[base + 2] = run; run += v2;
    if (base + 3 < n) out[base + 3] = run;
    if (t == 255) bsum[blockIdx.x] = sd[255];
}

// single-block exclusive scan of block sums (nb <= 256)
__global__ __launch_bounds__(256) void scan2_k(int* bsum, int nb) {
    __shared__ int sd[256];
    int t = threadIdx.x;
    sd[t] = (t < nb) ? bsum[t] : 0;
    __syncthreads();
    for (int off = 1; off < 256; off <<= 1) {
        int tmp = 0;
        if (t >= off) tmp = sd[t - off];
        __syncthreads();
        if (t >= off) sd[t] += tmp;
        __syncthreads();
    }
    if (t < nb) bsum[t] = (t > 0) ? sd[t - 1] : 0;
}

__global__ __launch_bounds__(256) void scanadd_k(int* __restrict__ out, const int* __restrict__ bsum,
                                                 int n, int E) {
    int i = blockIdx.x * 256 + threadIdx.x;
    if (i < n) out[i] += bsum[i >> 10];
    if (i == 0) out[n] = E;  // rowoff[n] = E
}

__global__ __launch_bounds__(256) void scatter_k(const int* __restrict__ src, const int* __restrict__ dst,
                                                 const int* __restrict__ rowoff, int* __restrict__ cursor,
                                                 int* __restrict__ perm, int E) {
    int i = blockIdx.x * 256 + threadIdx.x;
    if (i < E) {
        int d = dst[i];
        int p = atomicAdd(&cursor[d], 1);
        perm[rowoff[d] + p] = src[i];
    }
}

// ---------------------------------------------------------------------------
// Aggregation: one wave per dst node; VEC floats per lane (D = 64*VEC).
// Register accumulation, single coalesced write -> no float atomics.
// ---------------------------------------------------------------------------
template<int VEC>
__global__ __launch_bounds__(256) void aggregate_k(const float* __restrict__ x, const int* __restrict__ perm,
                                                   const int* __restrict__ rowoff, float* __restrict__ agg,
                                                   int n) {
    int node = (int)((blockIdx.x * 256 + threadIdx.x) >> 6);
    int lane = threadIdx.x & 63;
    if (node >= n) return;
    int beg = rowoff[node], end = rowoff[node + 1];
    float a0 = 0.f, a1 = 0.f, a2 = 0.f, a3 = 0.f;
    for (int e = beg; e < end; ++e) {
        int s = perm[e];
        if constexpr (VEC == 2) {
            const float2* row = (const float2*)(x + (size_t)s * 128);
            float2 r = row[lane];
            a0 += r.x; a1 += r.y;
        } else {
            const float4* row = (const float4*)(x + (size_t)s * 256);
            float4 r = row[lane];
            a0 += r.x; a1 += r.y; a2 += r.z; a3 += r.w;
        }
    }
    int c = end - beg;
    float inv = (c > 0) ? 1.0f / (float)c : 0.0f;
    if constexpr (VEC == 2) {
        float2* o = (float2*)(agg + (size_t)node * 128);
        o[lane] = make_float2(a0 * inv, a1 * inv);
    } else {
        float4* o = (float4*)(agg + (size_t)node * 256);
        o[lane] = make_float4(a0 * inv, a1 * inv, a2 * inv, a3 * inv);
    }
}

// ---------------------------------------------------------------------------
// Fused dual GEMM: C = [relu]( A1@W1 + A2@W2 + bias ), A row-major [M,K],
// W row-major [K,N]. 64x64 tile, BK=16, 4x4 per thread, A-tile transposed in
// LDS so both fragment reads are ds_read_b128. M must be a multiple of 64.
// ---------------------------------------------------------------------------
template<bool RELU>
__global__ __launch_bounds__(256) void gemm2_k(const float* __restrict__ A1, const float* __restrict__ A2,
                                               const float* __restrict__ W1, const float* __restrict__ W2,
                                               const float* __restrict__ bias, float* __restrict__ C,
                                               int M, int N, int K) {
    __shared__ float As[16][68];  // [k][m], pad keeps float4 alignment (68*4=272, 272%16==0)
    __shared__ float Bs[16][68];  // [k][n]
    int row0 = blockIdx.x * 64;
    int col0 = blockIdx.y * 64;
    int t = threadIdx.x;
    int tx = t & 15, ty = t >> 4;
    float acc[4][4] = {};
    bool colsFull = (col0 + 64 <= N) && ((N & 3) == 0);
    for (int p = 0; p < 2; ++p) {
        const float* A = p ? A2 : A1;
        const float* W = p ? W2 : W1;
        for (int k0 = 0; k0 < K; k0 += 16) {
            {   // A tile: thread t loads float4 (row r, k offset c4), stores transposed
                int r = t >> 2, c4 = (t & 3) * 4;
                float4 av = *(const float4*)(A + (size_t)(row0 + r) * K + k0 + c4);
                As[c4 + 0][r] = av.x;
                As[c4 + 1][r] = av.y;
                As[c4 + 2][r] = av.z;
                As[c4 + 3][r] = av.w;
            }
            if (colsFull) {
                int r = t >> 4, c4 = (t & 15) * 4;
                float4 wv = *(const float4*)(W + (size_t)(k0 + r) * N + col0 + c4);
                *(float4*)&Bs[r][c4] = wv;
            } else {
                #pragma unroll
                for (int i = 0; i < 4; ++i) {
                    int l = t + i * 256;
                    int r = l >> 6, c = l & 63;
                    int col = col0 + c;
                    Bs[r][c] = (col < N) ? W[(size_t)(k0 + r) * N + col] : 0.0f;
                }
            }
            __syncthreads();
            #pragma unroll
            for (int k = 0; k < 16; ++k) {
                float4 av = *(const float4*)&As[k][ty * 4];
                float4 bv = *(const float4*)&Bs[k][tx * 4];
                float a[4] = {av.x, av.y, av.z, av.w};
                float b[4] = {bv.x, bv.y, bv.z, bv.w};
                #pragma unroll
                for (int i = 0; i < 4; ++i)
                    #pragma unroll
                    for (int j = 0; j < 4; ++j)
                        acc[i][j] += a[i] * b[j];
            }
            __syncthreads();
        }
    }
    #pragma unroll
    for (int i = 0; i < 4; ++i) {
        int r = row0 + ty * 4 + i;
        #pragma unroll
        for (int j = 0; j < 4; ++j) {
            int col = col0 + tx * 4 + j;
            if (r < M && col < N) {
                float v = acc[i][j] + bias[col];
                if (RELU) v = fmaxf(v, 0.0f);
                C[(size_t)r * N + col] = v;
            }
        }
    }
}

// ---------------------------------------------------------------------------
// Row-wise log_softmax, in place. One wave per row (N <= 64).
// ---------------------------------------------------------------------------
__global__ __launch_bounds__(256) void logsoftmax_k(float* __restrict__ io, int M, int N) {
    int w = (int)((blockIdx.x * 256 + threadIdx.x) >> 6);
    int lane = threadIdx.x & 63;
    if (w >= M) return;
    float v = (lane < N) ? io[(size_t)w * N + lane] : -1e30f;
    float m = v;
    for (int off = 32; off > 0; off >>= 1) m = fmaxf(m, __shfl_xor(m, off));
    float e = (lane < N) ? expf(v - m) : 0.0f;
    float s = e;
    for (int off = 32; off > 0; off >>= 1) s += __shfl_xor(s, off);
    float r = v - m - logf(s);
    if (lane < N) io[(size_t)w * N + lane] = r;
}

// ---------------------------------------------------------------------------
extern "C" void kernel_launch(void* const* d_in, const int* in_sizes, int n_in,
                              void* d_out, int out_size, void* d_ws, size_t ws_size,
                              hipStream_t stream) {
    const float* x   = (const float*)d_in[0];
    const float* Wl0 = (const float*)d_in[1];
    const float* Wr0 = (const float*)d_in[2];
    const float* b0  = (const float*)d_in[3];
    const float* Wl1 = (const float*)d_in[4];
    const float* Wr1 = (const float*)d_in[5];
    const float* b1  = (const float*)d_in[6];
    const float* Wl2 = (const float*)d_in[7];
    const float* Wr2 = (const float*)d_in[8];
    const float* b2  = (const float*)d_in[9];
    const int* src0  = (const int*)d_in[10];
    const int* dst0  = (const int*)d_in[11];
    const int* src1  = (const int*)d_in[12];
    const int* dst1  = (const int*)d_in[13];
    const int* src2  = (const int*)d_in[14];
    const int* dst2  = (const int*)d_in[15];
    const int E0 = in_sizes[10], E1 = in_sizes[12], E2 = in_sizes[14];
    float* out = (float*)d_out;

    // workspace layout (~224 MB)
    char* w = (char*)d_ws;
    auto alloc = [&](size_t bytes) { char* p = w; w += (bytes + 255) & ~(size_t)255; return p; };
    float* agg0 = (float*)alloc((size_t)N1C * 128 * 4);
    float* h1   = (float*)alloc((size_t)N1C * 256 * 4);
    float* agg1 = (float*)alloc((size_t)N2C * 256 * 4);
    float* h2   = (float*)alloc((size_t)N2C * 256 * 4);
    float* agg2 = (float*)alloc((size_t)N3C * 256 * 4);
    int* zreg = (int*)alloc((size_t)2 * (N1C + N2C + N3C) * 4);  // cnt+cursor, all layers
    int* cnt0 = zreg;           int* cur0 = cnt0 + N1C;
    int* cnt1 = cur0 + N1C;     int* cur1 = cnt1 + N2C;
    int* cnt2 = cur1 + N2C;     int* cur2 = cnt2 + N3C;
    int* ro0   = (int*)alloc((size_t)(N1C + 1) * 4);
    int* ro1   = (int*)alloc((size_t)(N2C + 1) * 4);
    int* ro2   = (int*)alloc((size_t)(N3C + 1) * 4);
    int* perm0 = (int*)alloc((size_t)E0 * 4);
    int* perm1 = (int*)alloc((size_t)E1 * 4);
    int* perm2 = (int*)alloc((size_t)E2 * 4);
    int* bsum  = (int*)alloc(256 * 4);

    hipMemsetAsync(zreg, 0, (size_t)2 * (N1C + N2C + N3C) * 4, stream);

    auto csr = [&](const int* srcA, const int* dstA, int E, int n,
                   int* cnt, int* cur, int* ro, int* perm) {
        hist_k<<<dim3((E + 255) / 256), dim3(256), 0, stream>>>(dstA, cnt, E);
        int nb = (n + 1023) / 1024;
        scan1_k<<<dim3(nb), dim3(256), 0, stream>>>(cnt, ro, bsum, n);
        scan2_k<<<dim3(1), dim3(256), 0, stream>>>(bsum, nb);
        scanadd_k<<<dim3((n + 255) / 256), dim3(256), 0, stream>>>(ro, bsum, n, E);
        scatter_k<<<dim3((E + 255) / 256), dim3(256), 0, stream>>>(srcA, dstA, ro, cur, perm, E);
    };

    // layer 0: agg0 = mean_gather(x); h1 = relu(agg0@Wl0 + x[:N1]@Wr0 + b0)
    csr(src0, dst0, E0, N1C, cnt0, cur0, ro0, perm0);
    aggregate_k<2><<<dim3((N1C + 3) / 4), dim3(256), 0, stream>>>(x, perm0, ro0, agg0, N1C);
    gemm2_k<true><<<dim3(N1C / 64, 4), dim3(256), 0, stream>>>(agg0, x, Wl0, Wr0, b0, h1, N1C, 256, 128);

    // layer 1
    csr(src1, dst1, E1, N2C, cnt1, cur1, ro1, perm1);
    aggregate_k<4><<<dim3((N2C + 3) / 4), dim3(256), 0, stream>>>(h1, perm1, ro1, agg1, N2C);
    gemm2_k<true><<<dim3(N2C / 64, 4), dim3(256), 0, stream>>>(agg1, h1, Wl1, Wr1, b1, h2, N2C, 256, 256);

    // layer 2 (no relu) -> d_out, then in-place log_softmax
    csr(src2, dst2, E2, N3C, cnt2, cur2, ro2, perm2);
    aggregate_k<4><<<dim3((N3C + 3) / 4), dim3(256), 0, stream>>>(h2, perm2, ro2, agg2, N3C);
    gemm2_k<false><<<dim3(N3C / 64, 1), dim3(256), 0, stream>>>(agg2, h2, Wl2, Wr2, b2, out, N3C, 47, 256);
    logsoftmax_k<<<dim3((N3C + 3) / 4), dim3(256), 0, stream>>>(out, N3C, 47);
}

// Round 2
// 1779.878 us; speedup vs baseline: 1.1044x; 1.1044x over previous
//
#include <hip/hip_runtime.h>
#include <cstdint>
#include <cstddef>

// Problem constants (fixed instance per reference file)
#define N0C 1982464
#define N1C 123904
#define N2C 11264
#define N3C 1024
// D_IN=128, D_H=256, D_OUT=47

typedef __attribute__((ext_vector_type(8))) short bf16x8;
typedef __attribute__((ext_vector_type(4))) float f32x4;

__device__ __forceinline__ unsigned short f2b(float f) {
    unsigned u = __float_as_uint(f);
    unsigned r = (u + 0x7FFFu + ((u >> 16) & 1u)) >> 16;   // round-to-nearest-even
    return (unsigned short)r;
}
__device__ __forceinline__ float b2f(unsigned short h) {
    return __uint_as_float(((unsigned)h) << 16);
}

// ---------------------------------------------------------------------------
// CSR build: histogram -> exclusive scan -> scatter (src indices grouped by dst)
// ---------------------------------------------------------------------------
__global__ __launch_bounds__(256) void hist_k(const int* __restrict__ dst, int* __restrict__ cnt, int E) {
    int i = blockIdx.x * 256 + threadIdx.x;
    if (i < E) atomicAdd(&cnt[dst[i]], 1);
}

__global__ __launch_bounds__(256) void scan1_k(const int* __restrict__ in, int* __restrict__ out,
                                               int* __restrict__ bsum, int n) {
    __shared__ int sd[256];
    int t = threadIdx.x;
    int base = blockIdx.x * 1024 + t * 4;
    int v0 = (base + 0 < n) ? in[base + 0] : 0;
    int v1 = (base + 1 < n) ? in[base + 1] : 0;
    int v2 = (base + 2 < n) ? in[base + 2] : 0;
    int v3 = (base + 3 < n) ? in[base + 3] : 0;
    sd[t] = v0 + v1 + v2 + v3;
    __syncthreads();
    for (int off = 1; off < 256; off <<= 1) {
        int tmp = 0;
        if (t >= off) tmp = sd[t - off];
        __syncthreads();
        if (t >= off) sd[t] += tmp;
        __syncthreads();
    }
    int run = (t > 0) ? sd[t - 1] : 0;
    if (base + 0 < n) out[base + 0] = run; run += v0;
    if (base + 1 < n) out[base + 1] = run; run += v1;
    if (base + 2 < n) out[base + 2] = run; run += v2;
    if (base + 3 < n) out[base + 3] = run;
    if (t == 255) bsum[blockIdx.x] = sd[255];
}

__global__ __launch_bounds__(256) void scan2_k(int* bsum, int nb) {
    __shared__ int sd[256];
    int t = threadIdx.x;
    sd[t] = (t < nb) ? bsum[t] : 0;
    __syncthreads();
    for (int off = 1; off < 256; off <<= 1) {
        int tmp = 0;
        if (t >= off) tmp = sd[t - off];
        __syncthreads();
        if (t >= off) sd[t] += tmp;
        __syncthreads();
    }
    if (t < nb) bsum[t] = (t > 0) ? sd[t - 1] : 0;
}

__global__ __launch_bounds__(256) void scanadd_k(int* __restrict__ out, const int* __restrict__ bsum,
                                                 int n, int E) {
    int i = blockIdx.x * 256 + threadIdx.x;
    if (i < n) out[i] += bsum[i >> 10];
    if (i == 0) out[n] = E;
}

__global__ __launch_bounds__(256) void scatter_k(const int* __restrict__ src, const int* __restrict__ dst,
                                                 const int* __restrict__ rowoff, int* __restrict__ cursor,
                                                 int* __restrict__ perm, int E) {
    int i = blockIdx.x * 256 + threadIdx.x;
    if (i < E) {
        int d = dst[i];
        int p = atomicAdd(&cursor[d], 1);
        perm[rowoff[d] + p] = src[i];
    }
}

// ---------------------------------------------------------------------------
// Casts: x[:N1] fp32 -> bf16 ; weight fp32 [K][N] -> bf16 transposed [N][K]
// ---------------------------------------------------------------------------
__global__ __launch_bounds__(256) void castx_k(const float* __restrict__ x, unsigned short* __restrict__ xb,
                                               int n4) {
    int i = blockIdx.x * 256 + threadIdx.x;
    if (i < n4) {
        float4 v = ((const float4*)x)[i];
        ((ushort4*)xb)[i] = make_ushort4(f2b(v.x), f2b(v.y), f2b(v.z), f2b(v.w));
    }
}

__global__ __launch_bounds__(256) void castwt_k(const float* __restrict__ W, unsigned short* __restrict__ Wt,
                                                int K, int N) {
    int i = blockIdx.x * 256 + threadIdx.x;
    if (i < N * K) {
        int n = i / K, k = i - n * K;
        Wt[i] = f2b(W[(size_t)k * N + n]);
    }
}

// ---------------------------------------------------------------------------
// Aggregation (one wave per dst node, register accumulation, no float atomics)
// ---------------------------------------------------------------------------
// layer 0: x fp32 [*, 128] -> agg bf16 [n, 128]
__global__ __launch_bounds__(256) void agg0_k(const float* __restrict__ x, const int* __restrict__ perm,
                                              const int* __restrict__ ro, unsigned short* __restrict__ agg,
                                              int n) {
    int node = (int)((blockIdx.x * 256 + threadIdx.x) >> 6);
    int lane = threadIdx.x & 63;
    if (node >= n) return;
    int beg = ro[node], end = ro[node + 1];
    float a0 = 0.f, a1 = 0.f;
    for (int e = beg; e < end; ++e) {
        int s = perm[e];
        float2 r = ((const float2*)(x + (size_t)s * 128))[lane];
        a0 += r.x; a1 += r.y;
    }
    float inv = (end > beg) ? 1.0f / (float)(end - beg) : 0.0f;
    unsigned pack = (unsigned)f2b(a0 * inv) | ((unsigned)f2b(a1 * inv) << 16);
    ((unsigned*)(agg + (size_t)node * 128))[lane] = pack;
}

// layer 1: h bf16 [*, 256] -> agg bf16 [n, 256]
__global__ __launch_bounds__(256) void agg1_k(const unsigned short* __restrict__ h, const int* __restrict__ perm,
                                              const int* __restrict__ ro, unsigned short* __restrict__ agg,
                                              int n) {
    int node = (int)((blockIdx.x * 256 + threadIdx.x) >> 6);
    int lane = threadIdx.x & 63;
    if (node >= n) return;
    int beg = ro[node], end = ro[node + 1];
    float a0 = 0.f, a1 = 0.f, a2 = 0.f, a3 = 0.f;
    for (int e = beg; e < end; ++e) {
        int s = perm[e];
        ushort4 r = ((const ushort4*)(h + (size_t)s * 256))[lane];
        a0 += b2f(r.x); a1 += b2f(r.y); a2 += b2f(r.z); a3 += b2f(r.w);
    }
    float inv = (end > beg) ? 1.0f / (float)(end - beg) : 0.0f;
    ((ushort4*)(agg + (size_t)node * 256))[lane] =
        make_ushort4(f2b(a0 * inv), f2b(a1 * inv), f2b(a2 * inv), f2b(a3 * inv));
}

// layer 2: h fp32 [*, 256] -> agg fp32 [n, 256]
__global__ __launch_bounds__(256) void agg2_k(const float* __restrict__ x, const int* __restrict__ perm,
                                              const int* __restrict__ ro, float* __restrict__ agg, int n) {
    int node = (int)((blockIdx.x * 256 + threadIdx.x) >> 6);
    int lane = threadIdx.x & 63;
    if (node >= n) return;
    int beg = ro[node], end = ro[node + 1];
    float a0 = 0.f, a1 = 0.f, a2 = 0.f, a3 = 0.f;
    for (int e = beg; e < end; ++e) {
        int s = perm[e];
        float4 r = ((const float4*)(x + (size_t)s * 256))[lane];
        a0 += r.x; a1 += r.y; a2 += r.z; a3 += r.w;
    }
    float inv = (end > beg) ? 1.0f / (float)(end - beg) : 0.0f;
    ((float4*)(agg + (size_t)node * 256))[lane] = make_float4(a0 * inv, a1 * inv, a2 * inv, a3 * inv);
}

// ---------------------------------------------------------------------------
// bf16 MFMA dual GEMM: C = [relu]( A1@W1 + A2@W2 + bias ), N fixed at 256.
// A row-major [M,K] bf16; Wt = W^T row-major [256,K] bf16. Block = 64 rows x
// all 256 cols, 4 waves (wave w -> rows w*16..+15). fp32 accum in MFMA.
// ---------------------------------------------------------------------------
template<bool RELU, bool OUTBF16>
__global__ __launch_bounds__(256) void gemm_mfma_k(
    const unsigned short* __restrict__ A1, const unsigned short* __restrict__ A2,
    const unsigned short* __restrict__ Wt1, const unsigned short* __restrict__ Wt2,
    const float* __restrict__ bias, void* __restrict__ Cout, int M, int K) {
    __shared__ short As[64][40];    // [m][k], stride 40 bf16 (16B-aligned rows)
    __shared__ short Bs[256][40];   // [n][k]
    const int t = threadIdx.x;
    const int row0 = blockIdx.x * 64;
    const int wv = t >> 6, lane = t & 63;
    const int m16 = lane & 15, quad = lane >> 4;
    f32x4 acc[16] = {};
    for (int p = 0; p < 2; ++p) {
        const unsigned short* A  = p ? A2 : A1;
        const unsigned short* Wt = p ? Wt2 : Wt1;
        for (int k0 = 0; k0 < K; k0 += 32) {
            {   // stage A tile: 64 rows x 32 k, 16 B per thread
                int r = t >> 2, kc = (t & 3) * 8;
                *(int4*)&As[r][kc] = *(const int4*)(A + (size_t)(row0 + r) * K + k0 + kc);
            }
            {   // stage Bt tile: 256 n x 32 k, 64 B per thread
                const unsigned short* src = Wt + (size_t)t * K + k0;
                *(int4*)&Bs[t][0]  = *(const int4*)(src + 0);
                *(int4*)&Bs[t][8]  = *(const int4*)(src + 8);
                *(int4*)&Bs[t][16] = *(const int4*)(src + 16);
                *(int4*)&Bs[t][24] = *(const int4*)(src + 24);
            }
            __syncthreads();
            bf16x8 a = *(const bf16x8*)&As[wv * 16 + m16][quad * 8];
            #pragma unroll
            for (int c = 0; c < 16; ++c) {
                bf16x8 b = *(const bf16x8*)&Bs[c * 16 + m16][quad * 8];
                acc[c] = __builtin_amdgcn_mfma_f32_16x16x32_bf16(a, b, acc[c], 0, 0, 0);
            }
            __syncthreads();
        }
    }
    #pragma unroll
    for (int c = 0; c < 16; ++c) {
        int col = c * 16 + m16;
        float bv = bias[col];
        #pragma unroll
        for (int f = 0; f < 4; ++f) {
            int row = row0 + wv * 16 + quad * 4 + f;   // C/D: col=lane&15, row=quad*4+reg
            float v = acc[c][f] + bv;
            if (RELU) v = fmaxf(v, 0.0f);
            if (OUTBF16) ((unsigned short*)Cout)[(size_t)row * 256 + col] = f2b(v);
            else         ((float*)Cout)[(size_t)row * 256 + col] = v;
        }
    }
}

// ---------------------------------------------------------------------------
// fp32 vector GEMM (layer 2 only: M=1024, N=47, K=256)
// ---------------------------------------------------------------------------
template<bool RELU>
__global__ __launch_bounds__(256) void gemm2_k(const float* __restrict__ A1, const float* __restrict__ A2,
                                               const float* __restrict__ W1, const float* __restrict__ W2,
                                               const float* __restrict__ bias, float* __restrict__ C,
                                               int M, int N, int K) {
    __shared__ float As[16][68];
    __shared__ float Bs[16][68];
    int row0 = blockIdx.x * 64;
    int col0 = blockIdx.y * 64;
    int t = threadIdx.x;
    int tx = t & 15, ty = t >> 4;
    float acc[4][4] = {};
    bool colsFull = (col0 + 64 <= N) && ((N & 3) == 0);
    for (int p = 0; p < 2; ++p) {
        const float* A = p ? A2 : A1;
        const float* W = p ? W2 : W1;
        for (int k0 = 0; k0 < K; k0 += 16) {
            {
                int r = t >> 2, c4 = (t & 3) * 4;
                float4 av = *(const float4*)(A + (size_t)(row0 + r) * K + k0 + c4);
                As[c4 + 0][r] = av.x;
                As[c4 + 1][r] = av.y;
                As[c4 + 2][r] = av.z;
                As[c4 + 3][r] = av.w;
            }
            if (colsFull) {
                int r = t >> 4, c4 = (t & 15) * 4;
                float4 wv = *(const float4*)(W + (size_t)(k0 + r) * N + col0 + c4);
                *(float4*)&Bs[r][c4] = wv;
            } else {
                #pragma unroll
                for (int i = 0; i < 4; ++i) {
                    int l = t + i * 256;
                    int r = l >> 6, c = l & 63;
                    int col = col0 + c;
                    Bs[r][c] = (col < N) ? W[(size_t)(k0 + r) * N + col] : 0.0f;
                }
            }
            __syncthreads();
            #pragma unroll
            for (int k = 0; k < 16; ++k) {
                float4 av = *(const float4*)&As[k][ty * 4];
                float4 bv = *(const float4*)&Bs[k][tx * 4];
                float a[4] = {av.x, av.y, av.z, av.w};
                float b[4] = {bv.x, bv.y, bv.z, bv.w};
                #pragma unroll
                for (int i = 0; i < 4; ++i)
                    #pragma unroll
                    for (int j = 0; j < 4; ++j)
                        acc[i][j] += a[i] * b[j];
            }
            __syncthreads();
        }
    }
    #pragma unroll
    for (int i = 0; i < 4; ++i) {
        int r = row0 + ty * 4 + i;
        #pragma unroll
        for (int j = 0; j < 4; ++j) {
            int col = col0 + tx * 4 + j;
            if (r < M && col < N) {
                float v = acc[i][j] + bias[col];
                if (RELU) v = fmaxf(v, 0.0f);
                C[(size_t)r * N + col] = v;
            }
        }
    }
}

// ---------------------------------------------------------------------------
__global__ __launch_bounds__(256) void logsoftmax_k(float* __restrict__ io, int M, int N) {
    int w = (int)((blockIdx.x * 256 + threadIdx.x) >> 6);
    int lane = threadIdx.x & 63;
    if (w >= M) return;
    float v = (lane < N) ? io[(size_t)w * N + lane] : -1e30f;
    float m = v;
    for (int off = 32; off > 0; off >>= 1) m = fmaxf(m, __shfl_xor(m, off));
    float e = (lane < N) ? expf(v - m) : 0.0f;
    float s = e;
    for (int off = 32; off > 0; off >>= 1) s += __shfl_xor(s, off);
    float r = v - m - logf(s);
    if (lane < N) io[(size_t)w * N + lane] = r;
}

// ---------------------------------------------------------------------------
extern "C" void kernel_launch(void* const* d_in, const int* in_sizes, int n_in,
                              void* d_out, int out_size, void* d_ws, size_t ws_size,
                              hipStream_t stream) {
    const float* x   = (const float*)d_in[0];
    const float* Wl0 = (const float*)d_in[1];
    const float* Wr0 = (const float*)d_in[2];
    const float* b0  = (const float*)d_in[3];
    const float* Wl1 = (const float*)d_in[4];
    const float* Wr1 = (const float*)d_in[5];
    const float* b1  = (const float*)d_in[6];
    const float* Wl2 = (const float*)d_in[7];
    const float* Wr2 = (const float*)d_in[8];
    const float* b2  = (const float*)d_in[9];
    const int* src0  = (const int*)d_in[10];
    const int* dst0  = (const int*)d_in[11];
    const int* src1  = (const int*)d_in[12];
    const int* dst1  = (const int*)d_in[13];
    const int* src2  = (const int*)d_in[14];
    const int* dst2  = (const int*)d_in[15];
    const int E0 = in_sizes[10], E1 = in_sizes[12], E2 = in_sizes[14];
    float* out = (float*)d_out;

    // workspace layout
    char* w = (char*)d_ws;
    auto alloc = [&](size_t bytes) { char* p = w; w += (bytes + 255) & ~(size_t)255; return p; };
    unsigned short* agg0 = (unsigned short*)alloc((size_t)N1C * 128 * 2);  // bf16
    unsigned short* xb   = (unsigned short*)alloc((size_t)N1C * 128 * 2);  // bf16 x[:N1]
    unsigned short* h1   = (unsigned short*)alloc((size_t)N1C * 256 * 2);  // bf16
    unsigned short* agg1 = (unsigned short*)alloc((size_t)N2C * 256 * 2);  // bf16
    float* h2   = (float*)alloc((size_t)N2C * 256 * 4);
    float* agg2 = (float*)alloc((size_t)N3C * 256 * 4);
    unsigned short* Wt0l = (unsigned short*)alloc((size_t)256 * 128 * 2);
    unsigned short* Wt0r = (unsigned short*)alloc((size_t)256 * 128 * 2);
    unsigned short* Wt1l = (unsigned short*)alloc((size_t)256 * 256 * 2);
    unsigned short* Wt1r = (unsigned short*)alloc((size_t)256 * 256 * 2);
    int* zreg = (int*)alloc((size_t)2 * (N1C + N2C + N3C) * 4);
    int* cnt0 = zreg;           int* cur0 = cnt0 + N1C;
    int* cnt1 = cur0 + N1C;     int* cur1 = cnt1 + N2C;
    int* cnt2 = cur1 + N2C;     int* cur2 = cnt2 + N3C;
    int* ro0   = (int*)alloc((size_t)(N1C + 1) * 4);
    int* ro1   = (int*)alloc((size_t)(N2C + 1) * 4);
    int* ro2   = (int*)alloc((size_t)(N3C + 1) * 4);
    int* perm0 = (int*)alloc((size_t)E0 * 4);
    int* perm1 = (int*)alloc((size_t)E1 * 4);
    int* perm2 = (int*)alloc((size_t)E2 * 4);
    int* bsum  = (int*)alloc(256 * 4);

    hipMemsetAsync(zreg, 0, (size_t)2 * (N1C + N2C + N3C) * 4, stream);

    auto csr = [&](const int* srcA, const int* dstA, int E, int n,
                   int* cnt, int* cur, int* ro, int* perm) {
        hist_k<<<dim3((E + 255) / 256), dim3(256), 0, stream>>>(dstA, cnt, E);
        int nb = (n + 1023) / 1024;
        scan1_k<<<dim3(nb), dim3(256), 0, stream>>>(cnt, ro, bsum, n);
        scan2_k<<<dim3(1), dim3(256), 0, stream>>>(bsum, nb);
        scanadd_k<<<dim3((n + 255) / 256), dim3(256), 0, stream>>>(ro, bsum, n, E);
        scatter_k<<<dim3((E + 255) / 256), dim3(256), 0, stream>>>(srcA, dstA, ro, cur, perm, E);
    };

    // weight casts (tiny) + x[:N1] cast
    castwt_k<<<dim3((256 * 128 + 255) / 256), dim3(256), 0, stream>>>(Wl0, Wt0l, 128, 256);
    castwt_k<<<dim3((256 * 128 + 255) / 256), dim3(256), 0, stream>>>(Wr0, Wt0r, 128, 256);
    castwt_k<<<dim3((256 * 256 + 255) / 256), dim3(256), 0, stream>>>(Wl1, Wt1l, 256, 256);
    castwt_k<<<dim3((256 * 256 + 255) / 256), dim3(256), 0, stream>>>(Wr1, Wt1r, 256, 256);
    castx_k<<<dim3((N1C * 128 / 4 + 255) / 256), dim3(256), 0, stream>>>(x, xb, N1C * 128 / 4);

    // layer 0
    csr(src0, dst0, E0, N1C, cnt0, cur0, ro0, perm0);
    agg0_k<<<dim3((N1C + 3) / 4), dim3(256), 0, stream>>>(x, perm0, ro0, agg0, N1C);
    gemm_mfma_k<true, true><<<dim3(N1C / 64), dim3(256), 0, stream>>>(agg0, xb, Wt0l, Wt0r, b0, h1, N1C, 128);

    // layer 1
    csr(src1, dst1, E1, N2C, cnt1, cur1, ro1, perm1);
    agg1_k<<<dim3((N2C + 3) / 4), dim3(256), 0, stream>>>(h1, perm1, ro1, agg1, N2C);
    gemm_mfma_k<true, false><<<dim3(N2C / 64), dim3(256), 0, stream>>>(agg1, h1, Wt1l, Wt1r, b1, h2, N2C, 256);

    // layer 2 (fp32) -> d_out, then in-place log_softmax
    csr(src2, dst2, E2, N3C, cnt2, cur2, ro2, perm2);
    agg2_k<<<dim3((N3C + 3) / 4), dim3(256), 0, stream>>>(h2, perm2, ro2, agg2, N3C);
    gemm2_k<false><<<dim3(N3C / 64, 1), dim3(256), 0, stream>>>(agg2, h2, Wl2, Wr2, b2, out, N3C, 47, 256);
    logsoftmax_k<<<dim3((N3C + 3) / 4), dim3(256), 0, stream>>>(out, N3C, 47);
}